// Round 3
// baseline (693.774 us; speedup 1.0000x reference)
//
#include <hip/hip_runtime.h>
#include <hip/hip_fp16.h>

// DGCNN forward, fully fused: one workgroup per graph, 2 blocks/CU co-resident.
// f32 everywhere on the sort-key-critical chain; h1/h2 archived to global
// scratch as f16 (conv features only); h3 read back from LDS in f32.

#define TPB   1024
#define GRID  512
#define MG    200
#define EPG   6400
#define EE    (512 * EPG)

// ---- LDS layout (byte offsets). Total 78,336 B -> 2 blocks/CU (156.7/160 KiB) ----
#define OFF_BUFX 0        // f32[201*36] rows 0..200 (row 200 = zeros); later topv[30][100] + conv W
#define OFF_HCUR 28944    // f32[200*36] current-layer h (f32); later conv scratch
#define OFF_CSR  57744    // u8[7200]    CSR (rows padded to x4 entries, pad -> 200)
#define OFF_ROFF 64944    // i32[201] row offsets (padded units)
#define OFF_CNT  65760    // i32[200] degree counts   \ scl f32[201] aliases CNT..CUR
#define OFF_CUR  66560    // i32[200] cursors         /
#define OFF_DINV 67360    // f32[200]
#define OFF_H4   68160    // f32[200] sort key
#define OFF_RANK 68960    // i32[200]
#define OFF_ORD  69760    // i32[30]
#define OFF_BIAS 69880    // f32[48]
#define OFF_RED  70072    // f32[16] (+8 pad)
#define OFF_WREG 70144    // f32[2048] current weight stage (W1 in halves)
#define SMEM_BYTES 78336

__global__ __launch_bounds__(TPB, 8) void dgcnn_kernel(
    const float* __restrict__ x,
    const int*   __restrict__ ei,
    const float* __restrict__ W1, const float* __restrict__ b1,
    const float* __restrict__ W2, const float* __restrict__ b2,
    const float* __restrict__ W3, const float* __restrict__ b3,
    const float* __restrict__ W4, const float* __restrict__ b4,
    const float* __restrict__ cW1, const float* __restrict__ cb1,
    const float* __restrict__ cW2, const float* __restrict__ cb2,
    const float* __restrict__ lW1, const float* __restrict__ lb1,
    const float* __restrict__ lW2, const float* __restrict__ lb2,
    __half* __restrict__ arch,     // [512][200][64] f16 archive of h1|h2
    float* __restrict__ out)
{
    extern __shared__ unsigned char smem[];
    float* bufX = (float*)(smem + OFF_BUFX);
    float* hcur = (float*)(smem + OFF_HCUR);
    unsigned char* csr = (unsigned char*)(smem + OFF_CSR);
    int*   roff = (int*)(smem + OFF_ROFF);
    int*   cnt  = (int*)(smem + OFF_CNT);
    int*   cur  = (int*)(smem + OFF_CUR);
    float* dinv = (float*)(smem + OFF_DINV);
    float* h4k  = (float*)(smem + OFF_H4);
    int*   rank = (int*)(smem + OFF_RANK);
    int*   ord  = (int*)(smem + OFF_ORD);
    float* bias = (float*)(smem + OFF_BIAS);
    float* red  = (float*)(smem + OFF_RED);
    float* wreg = (float*)(smem + OFF_WREG);

    const int g = blockIdx.x;
    const int t = threadIdx.x;
    const int gbase = g * MG;
    const float* xg   = x + (size_t)gbase * 128;
    const int*   srcp = ei + (size_t)g * EPG;
    const int*   dstp = ei + (size_t)EE + (size_t)g * EPG;

    // ---------------- Phase A: stage W1 half 1, zero counters + zero row ----------------
    for (int idx = t; idx < 2048; idx += TPB) wreg[idx] = W1[idx];
    if (t < 32) bias[t] = b1[t];
    if (t < MG) { cnt[t] = 0; rank[t] = 0; }
    if (t >= 512 && t < 548) bufX[200 * 36 + (t - 512)] = 0.f;   // zero row 200
    __syncthreads();

    // ---------------- Phase B: in-degree count ----------------
    for (int e = t; e < EPG; e += TPB) atomicAdd(&cnt[dstp[e] - gbase], 1);
    __syncthreads();

    // ---------------- Phase C: dinv + prefix scan over PADDED row lengths ----------------
    if (t >= 256 && t < 256 + MG) {
        int i = t - 256;
        dinv[i] = 1.0f / sqrtf((float)(cnt[i] + 1));
    }
    if (t < 64) {
        if (t == 0) roff[0] = 0;
        int carry = 0;
        #pragma unroll
        for (int c = 0; c < 4; ++c) {
            const int i = c * 64 + t;
            int v = (i < MG) ? ((cnt[i] + 4) & ~3) : 0;   // self-loop +1, pad to x4
            #pragma unroll
            for (int off = 1; off < 64; off <<= 1) {
                int u = __shfl_up(v, off);
                if (t >= (int)off) v += u;
            }
            if (i < MG) roff[i + 1] = carry + v;
            carry += __shfl(v, 63);
        }
    }
    __syncthreads();

    // ---------------- Phase D: self-loop entry + cursors ----------------
    if (t < MG) {
        int p = roff[t];
        csr[p] = (unsigned char)t;
        cur[t] = p + 1;
    }
    __syncthreads();

    // ---------------- Phase E: CSR placement ----------------
    for (int e = t; e < EPG; e += TPB) {
        int d = dstp[e] - gbase;
        int s = srcp[e] - gbase;
        int p = atomicAdd(&cur[d], 1);
        csr[p] = (unsigned char)s;
    }
    __syncthreads();

    // ---------------- Phase F: fill padding slots with zero-row index 200 ----------------
    if (t < MG) {
        for (int p = cur[t]; p < roff[t + 1]; ++p) csr[p] = (unsigned char)200;
    }
    __syncthreads();

    const int f32lane = t & 31;
    const int islot   = t >> 5;   // 0..31

    // agg: hcur[d][f] = tanh(dinv[d]*sum_{p} bufX[csr[p]][f] + bias[f]);
    // archOff >= 0: also archive result to global as f16 at column offset archOff.
    auto agg_layer = [&](int archOff) {
        const int fq  = t & 7;
        const int f4  = fq << 2;
        const int dsl = t >> 3;   // 0..127
        for (int d = dsl; d < MG; d += 128) {
            const int p0 = roff[d], p1 = roff[d + 1];
            float a0 = 0.f, a1 = 0.f, a2 = 0.f, a3 = 0.f;
            float c0 = 0.f, c1v = 0.f, c2v = 0.f, c3v = 0.f;
            for (int p = p0; p < p1; p += 4) {
                const unsigned q = *(const unsigned*)(csr + p);
                const float4 v0 = *(const float4*)(bufX + (q & 255u) * 36 + f4);
                const float4 v1 = *(const float4*)(bufX + ((q >> 8) & 255u) * 36 + f4);
                const float4 v2 = *(const float4*)(bufX + ((q >> 16) & 255u) * 36 + f4);
                const float4 v3 = *(const float4*)(bufX + (q >> 24) * 36 + f4);
                a0 += v0.x; a1 += v0.y; a2 += v0.z; a3 += v0.w;
                c0 += v1.x; c1v += v1.y; c2v += v1.z; c3v += v1.w;
                a0 += v2.x; a1 += v2.y; a2 += v2.z; a3 += v2.w;
                c0 += v3.x; c1v += v3.y; c2v += v3.z; c3v += v3.w;
            }
            const float dv = dinv[d];
            float o0 = tanhf(dv * (a0 + c0)  + bias[f4 + 0]);
            float o1 = tanhf(dv * (a1 + c1v) + bias[f4 + 1]);
            float o2 = tanhf(dv * (a2 + c2v) + bias[f4 + 2]);
            float o3 = tanhf(dv * (a3 + c3v) + bias[f4 + 3]);
            *(float4*)(hcur + d * 36 + f4) = make_float4(o0, o1, o2, o3);
            if (archOff >= 0) {
                __half hx[4] = { __float2half_rn(o0), __float2half_rn(o1),
                                 __float2half_rn(o2), __float2half_rn(o3) };
                *(uint2*)(arch + (size_t)(gbase + d) * 64 + archOff + f4) = *(uint2*)hx;
            }
        }
    };

    auto gemm_mid = [&](const float* __restrict__ src) {
        // bufX = (src[200x32] @ W[32x32]) scaled by dinv[row]
        const int f = f32lane;
        {
            float acc0 = 0.f, acc1 = 0.f, acc2 = 0.f, acc3 = 0.f;
            #pragma unroll
            for (int k4 = 0; k4 < 8; ++k4) {
                const float w0 = wreg[k4 * 128 + 0  + f];
                const float w1 = wreg[k4 * 128 + 32 + f];
                const float w2 = wreg[k4 * 128 + 64 + f];
                const float w3 = wreg[k4 * 128 + 96 + f];
                float4 v;
                v = *(const float4*)(src + (islot      ) * 36 + k4 * 4); acc0 += v.x*w0 + v.y*w1 + v.z*w2 + v.w*w3;
                v = *(const float4*)(src + (islot + 32 ) * 36 + k4 * 4); acc1 += v.x*w0 + v.y*w1 + v.z*w2 + v.w*w3;
                v = *(const float4*)(src + (islot + 64 ) * 36 + k4 * 4); acc2 += v.x*w0 + v.y*w1 + v.z*w2 + v.w*w3;
                v = *(const float4*)(src + (islot + 96 ) * 36 + k4 * 4); acc3 += v.x*w0 + v.y*w1 + v.z*w2 + v.w*w3;
            }
            bufX[(islot      ) * 36 + f] = dinv[islot      ] * acc0;
            bufX[(islot + 32 ) * 36 + f] = dinv[islot + 32 ] * acc1;
            bufX[(islot + 64 ) * 36 + f] = dinv[islot + 64 ] * acc2;
            bufX[(islot + 96 ) * 36 + f] = dinv[islot + 96 ] * acc3;
        }
        {
            const int i2  = islot + 192;
            const int i2c = i2 < MG ? i2 : (MG - 1);
            float acc0 = 0.f, acc1 = 0.f, acc2 = 0.f;
            #pragma unroll
            for (int k4 = 0; k4 < 8; ++k4) {
                const float w0 = wreg[k4 * 128 + 0  + f];
                const float w1 = wreg[k4 * 128 + 32 + f];
                const float w2 = wreg[k4 * 128 + 64 + f];
                const float w3 = wreg[k4 * 128 + 96 + f];
                float4 v;
                v = *(const float4*)(src + (islot + 128) * 36 + k4 * 4); acc0 += v.x*w0 + v.y*w1 + v.z*w2 + v.w*w3;
                v = *(const float4*)(src + (islot + 160) * 36 + k4 * 4); acc1 += v.x*w0 + v.y*w1 + v.z*w2 + v.w*w3;
                v = *(const float4*)(src + (i2c        ) * 36 + k4 * 4); acc2 += v.x*w0 + v.y*w1 + v.z*w2 + v.w*w3;
            }
            bufX[(islot + 128) * 36 + f] = dinv[islot + 128] * acc0;
            bufX[(islot + 160) * 36 + f] = dinv[islot + 160] * acc1;
            if (i2 < MG) bufX[i2 * 36 + f] = dinv[i2] * acc2;
        }
    };

    // ---------------- Layer 1 GEMM: x[200x128] @ W1[128x32], W1 staged in halves ----------
    {
        const int f = f32lane;
        const int r6 = islot + 192;
        float acc[7] = {0.f,0.f,0.f,0.f,0.f,0.f,0.f};
        const float4* xv = (const float4*)xg;
        #pragma unroll 4
        for (int k4 = 0; k4 < 16; ++k4) {
            const float w0 = wreg[k4 * 128 + 0  + f];
            const float w1 = wreg[k4 * 128 + 32 + f];
            const float w2 = wreg[k4 * 128 + 64 + f];
            const float w3 = wreg[k4 * 128 + 96 + f];
            #pragma unroll
            for (int rr = 0; rr < 6; ++rr) {
                const float4 v = xv[(islot + 32 * rr) * 32 + k4];
                acc[rr] += v.x*w0 + v.y*w1 + v.z*w2 + v.w*w3;
            }
            if (r6 < MG) {
                const float4 v = xv[r6 * 32 + k4];
                acc[6] += v.x*w0 + v.y*w1 + v.z*w2 + v.w*w3;
            }
        }
        __syncthreads();
        for (int idx = t; idx < 2048; idx += TPB) wreg[idx] = W1[2048 + idx];
        __syncthreads();
        #pragma unroll 4
        for (int k4 = 16; k4 < 32; ++k4) {
            const float w0 = wreg[(k4 - 16) * 128 + 0  + f];
            const float w1 = wreg[(k4 - 16) * 128 + 32 + f];
            const float w2 = wreg[(k4 - 16) * 128 + 64 + f];
            const float w3 = wreg[(k4 - 16) * 128 + 96 + f];
            #pragma unroll
            for (int rr = 0; rr < 6; ++rr) {
                const float4 v = xv[(islot + 32 * rr) * 32 + k4];
                acc[rr] += v.x*w0 + v.y*w1 + v.z*w2 + v.w*w3;
            }
            if (r6 < MG) {
                const float4 v = xv[r6 * 32 + k4];
                acc[6] += v.x*w0 + v.y*w1 + v.z*w2 + v.w*w3;
            }
        }
        #pragma unroll
        for (int rr = 0; rr < 6; ++rr) {
            const int row = islot + 32 * rr;
            bufX[row * 36 + f] = dinv[row] * acc[rr];
        }
        if (r6 < MG) bufX[r6 * 36 + f] = dinv[r6] * acc[6];
    }
    __syncthreads();
    agg_layer(0);    // h1 -> arch[:,0:32)
    __syncthreads();

    // ---------------- Layer 2 ----------------
    for (int idx = t; idx < 1024; idx += TPB) wreg[idx] = W2[idx];
    if (t < 32) bias[t] = b2[t];
    __syncthreads();
    gemm_mid(hcur);
    __syncthreads();
    agg_layer(32);   // h2 -> arch[:,32:64)
    __syncthreads();

    // ---------------- Layer 3 ----------------
    for (int idx = t; idx < 1024; idx += TPB) wreg[idx] = W3[idx];
    if (t < 32) bias[t] = b3[t];
    __syncthreads();
    gemm_mid(hcur);
    __syncthreads();
    agg_layer(-1);   // h3 stays in hcur (f32), not archived
    __syncthreads();

    // ---------------- Layer 4 (Fout=1): scl = dinv * (h3 @ W4); scl[200]=0 ----------------
    float* scl = (float*)(smem + OFF_CNT);   // 400 floats available (cnt+cur dead)
    if (t < MG) {
        float a = 0.f;
        #pragma unroll 8
        for (int k = 0; k < 32; ++k) a += hcur[t * 36 + k] * W4[k];
        scl[t] = dinv[t] * a;
    }
    if (t == 512) scl[200] = 0.f;
    __syncthreads();
    if (t < MG) {
        const int p0 = roff[t], p1 = roff[t + 1];
        float s = 0.f;
        for (int p = p0; p < p1; p += 4) {
            const unsigned q = *(const unsigned*)(csr + p);
            s += scl[q & 255u] + scl[(q >> 8) & 255u]
               + scl[(q >> 16) & 255u] + scl[q >> 24];
        }
        h4k[t] = tanhf(dinv[t] * s + b4[0]);
    }
    __syncthreads();

    // ---------------- SortPool: exact stable rank (desc value, asc index) ----------------
    if (t < 512) {
        const int i = t & 255;
        const int half = t >> 8;
        if (i < MG) {
            const float vi = h4k[i];
            int r = 0;
            const int j0 = half * 100, j1 = half * 100 + 100;
            for (int j = j0; j < j1; ++j) {
                const float vj = h4k[j];
                r += (vj > vi || (vj == vi && j < i)) ? 1 : 0;
            }
            atomicAdd(&rank[i], r);
        }
    }
    __syncthreads();
    if (t < MG) {
        const int r = rank[t];
        if (r < 30) ord[r] = t;
    }
    __syncthreads();

    // ---------------- Stage conv weights (bufX tail) + gather top-30 features ----------
    float* topv = bufX;           // [30][100] = 3000 floats
    float* cw   = bufX + 3104;    // cW1: [0,1552)  cW2: [1552,4112); ends at 7216 <= 7236
    for (int idx = t; idx < 1552; idx += TPB) cw[idx] = cW1[idx];
    for (int idx = t; idx < 2560; idx += TPB) cw[1552 + idx] = cW2[idx];
    if (t < 16) bias[t] = cb1[t];
    else if (t < 48) bias[t] = cb2[t - 16];
    for (int idx = t; idx < 2910; idx += TPB) {   // 30*97 (R2 bug: was if(t<2910))
        const int kk = idx / 97;
        const int ff = idx - kk * 97;
        const int nd = ord[kk];
        float v;
        if      (ff < 64) v = __half2float(arch[(size_t)(gbase + nd) * 64 + ff]);
        else if (ff < 96) v = hcur[nd * 36 + (ff - 64)];   // h3, f32
        else              v = h4k[nd];
        topv[kk * 100 + ff] = v;
    }
    __syncthreads();

    // conv scratch in hcur (dead after gather barrier)
    float* c1p2 = hcur;           // [16][30]
    float* c1pl = hcur + 480;     // [16][16]
    float* flat = hcur + 736;     // [352]
    float* hlin = hcur + 1088;    // [128]

    // ---------------- Conv1 (97->16 per slot) + ReLU ----------------
    if (t < 480) {
        const int o  = t & 15;
        const int tt = t >> 4;
        float a = bias[o];
        const float* wrow = cw + o * 97;
        const float* trow = topv + tt * 100;
        #pragma unroll 4
        for (int f = 0; f < 97; ++f) a += wrow[f] * trow[f];
        c1p2[o * 30 + tt] = fmaxf(a, 0.f);
    }
    __syncthreads();

    // ---------------- MaxPool1d(2,2): 30 -> 15 ----------------
    if (t < 240) {
        const int o  = t & 15;
        const int tp = t >> 4;
        c1pl[o * 16 + tp] = fmaxf(c1p2[o * 30 + 2 * tp], c1p2[o * 30 + 2 * tp + 1]);
    }
    __syncthreads();

    // ---------------- Conv2 (16->32, k=5) + ReLU -> flat; init hlin ----------------
    if (t < 352) {
        const int o  = t & 31;
        const int tt = t >> 5;
        float a = bias[16 + o];
        const float* w2r = cw + 1552 + o * 80;
        #pragma unroll
        for (int i2 = 0; i2 < 16; ++i2) {
            #pragma unroll
            for (int kk = 0; kk < 5; ++kk)
                a += w2r[i2 * 5 + kk] * c1pl[i2 * 16 + tt + kk];
        }
        flat[o * 11 + tt] = fmaxf(a, 0.f);
    } else if (t >= 512 && t < 640) {
        hlin[t - 512] = lb1[t - 512];
    }
    __syncthreads();

    // ---------------- Linear 352->128 (split-K over 8 groups) ----------------
    {
        const int f  = t & 127;
        const int kc = t >> 7;
        float a = 0.f;
        const int k0 = kc * 44;
        #pragma unroll 4
        for (int kk = k0; kk < k0 + 44; ++kk) a += flat[kk] * lW1[kk * 128 + f];
        atomicAdd(&hlin[f], a);
    }
    __syncthreads();

    // ---------------- ReLU -> Linear 128->1 -> sigmoid ----------------
    if (t < 128) {
        float p = fmaxf(hlin[t], 0.f) * lW2[t];
        #pragma unroll
        for (int off = 32; off > 0; off >>= 1) p += __shfl_down(p, off);
        if ((t & 63) == 0) red[t >> 6] = p;
    }
    __syncthreads();
    if (t == 0) {
        const float z = red[0] + red[1] + lb2[0];
        out[g] = 1.f / (1.f + expf(-z));
    }
}

extern "C" void kernel_launch(void* const* d_in, const int* in_sizes, int n_in,
                              void* d_out, int out_size, void* d_ws, size_t ws_size,
                              hipStream_t stream) {
    (void)in_sizes; (void)n_in; (void)out_size; (void)ws_size;
    const float* x   = (const float*)d_in[0];
    const int*   ei  = (const int*)d_in[1];
    const float* W1  = (const float*)d_in[3];  const float* b1  = (const float*)d_in[4];
    const float* W2  = (const float*)d_in[5];  const float* b2  = (const float*)d_in[6];
    const float* W3  = (const float*)d_in[7];  const float* b3  = (const float*)d_in[8];
    const float* W4  = (const float*)d_in[9];  const float* b4  = (const float*)d_in[10];
    const float* cW1 = (const float*)d_in[11]; const float* cb1 = (const float*)d_in[12];
    const float* cW2 = (const float*)d_in[13]; const float* cb2 = (const float*)d_in[14];
    const float* lW1 = (const float*)d_in[15]; const float* lb1 = (const float*)d_in[16];
    const float* lW2 = (const float*)d_in[17]; const float* lb2 = (const float*)d_in[18];
    float* out = (float*)d_out;
    __half* arch = (__half*)d_ws;   // needs 512*200*64*2 = 13.1 MB

    hipFuncSetAttribute((const void*)dgcnn_kernel,
                        hipFuncAttributeMaxDynamicSharedMemorySize, SMEM_BYTES);

    dgcnn_kernel<<<GRID, TPB, SMEM_BYTES, stream>>>(
        x, ei, W1, b1, W2, b2, W3, b3, W4, b4,
        cW1, cb1, cW2, cb2, lW1, lb1, lW2, lb2, arch, out);
}

// Round 4
// 330.457 us; speedup vs baseline: 2.0994x; 2.0994x over previous
//
#include <hip/hip_runtime.h>
#include <hip/hip_fp16.h>

// DGCNN forward, fully fused: one workgroup per graph, 2 blocks/CU co-resident.
// f32 everywhere on the sort-key-critical chain; h1/h2 archived to global
// scratch as f16 (conv features only); h3 read back from LDS in f32.
// All hot loops use named scalar accumulators: VGPR must stay <= 64 for
// 2 blocks/CU (R3 regression: acc arrays + deep unroll -> scratch spills,
// 2 GB of HBM spill traffic).

#define TPB   1024
#define GRID  512
#define MG    200
#define EPG   6400
#define EE    (512 * EPG)

// ---- LDS layout (byte offsets). Total 78,336 B -> 2 blocks/CU (156.7/160 KiB) ----
#define OFF_BUFX 0        // f32[201*36] rows 0..200 (row 200 = zeros); later topv[30][100] + conv W
#define OFF_HCUR 28944    // f32[200*36] current-layer h (f32); later conv scratch
#define OFF_CSR  57744    // u8[7200]    CSR (rows padded to x4 entries, pad -> 200)
#define OFF_ROFF 64944    // i32[201] row offsets (padded units)
#define OFF_CNT  65760    // i32[200] degree counts   \ scl f32[201] aliases CNT..CUR
#define OFF_CUR  66560    // i32[200] cursors         /
#define OFF_DINV 67360    // f32[200]
#define OFF_H4   68160    // f32[200] sort key
#define OFF_RANK 68960    // i32[200]
#define OFF_ORD  69760    // i32[30]
#define OFF_BIAS 69880    // f32[48]
#define OFF_RED  70072    // f32[16] (+8 pad)
#define OFF_WREG 70144    // f32[2048] current weight stage (W1 in 8KB halves)
#define SMEM_BYTES 78336

__global__ __launch_bounds__(TPB, 8) void dgcnn_kernel(
    const float* __restrict__ x,
    const int*   __restrict__ ei,
    const float* __restrict__ W1, const float* __restrict__ b1,
    const float* __restrict__ W2, const float* __restrict__ b2,
    const float* __restrict__ W3, const float* __restrict__ b3,
    const float* __restrict__ W4, const float* __restrict__ b4,
    const float* __restrict__ cW1, const float* __restrict__ cb1,
    const float* __restrict__ cW2, const float* __restrict__ cb2,
    const float* __restrict__ lW1, const float* __restrict__ lb1,
    const float* __restrict__ lW2, const float* __restrict__ lb2,
    __half* __restrict__ arch,     // [512][200][64] f16 archive of h1|h2
    float* __restrict__ out)
{
    extern __shared__ unsigned char smem[];
    float* bufX = (float*)(smem + OFF_BUFX);
    float* hcur = (float*)(smem + OFF_HCUR);
    unsigned char* csr = (unsigned char*)(smem + OFF_CSR);
    int*   roff = (int*)(smem + OFF_ROFF);
    int*   cnt  = (int*)(smem + OFF_CNT);
    int*   cur  = (int*)(smem + OFF_CUR);
    float* dinv = (float*)(smem + OFF_DINV);
    float* h4k  = (float*)(smem + OFF_H4);
    int*   rank = (int*)(smem + OFF_RANK);
    int*   ord  = (int*)(smem + OFF_ORD);
    float* bias = (float*)(smem + OFF_BIAS);
    float* red  = (float*)(smem + OFF_RED);
    float* wreg = (float*)(smem + OFF_WREG);

    const int g = blockIdx.x;
    const int t = threadIdx.x;
    const int gbase = g * MG;
    const float* xg   = x + (size_t)gbase * 128;
    const int*   srcp = ei + (size_t)g * EPG;
    const int*   dstp = ei + (size_t)EE + (size_t)g * EPG;

    // ---------------- Phase A: stage W1 half 1, zero counters + zero row ----------------
    for (int idx = t; idx < 2048; idx += TPB) wreg[idx] = W1[idx];
    if (t < 32) bias[t] = b1[t];
    if (t < MG) { cnt[t] = 0; rank[t] = 0; }
    if (t >= 512 && t < 548) bufX[200 * 36 + (t - 512)] = 0.f;   // zero row 200
    __syncthreads();

    // ---------------- Phase B: in-degree count ----------------
    for (int e = t; e < EPG; e += TPB) atomicAdd(&cnt[dstp[e] - gbase], 1);
    __syncthreads();

    // ---------------- Phase C: dinv + prefix scan over PADDED row lengths ----------------
    if (t >= 256 && t < 256 + MG) {
        int i = t - 256;
        dinv[i] = 1.0f / sqrtf((float)(cnt[i] + 1));
    }
    if (t < 64) {
        if (t == 0) roff[0] = 0;
        int carry = 0;
        #pragma unroll
        for (int c = 0; c < 4; ++c) {
            const int i = c * 64 + t;
            int v = (i < MG) ? ((cnt[i] + 4) & ~3) : 0;   // self-loop +1, pad to x4
            #pragma unroll
            for (int off = 1; off < 64; off <<= 1) {
                int u = __shfl_up(v, off);
                if (t >= (int)off) v += u;
            }
            if (i < MG) roff[i + 1] = carry + v;
            carry += __shfl(v, 63);
        }
    }
    __syncthreads();

    // ---------------- Phase D: self-loop entry + cursors ----------------
    if (t < MG) {
        int p = roff[t];
        csr[p] = (unsigned char)t;
        cur[t] = p + 1;
    }
    __syncthreads();

    // ---------------- Phase E: CSR placement ----------------
    for (int e = t; e < EPG; e += TPB) {
        int d = dstp[e] - gbase;
        int s = srcp[e] - gbase;
        int p = atomicAdd(&cur[d], 1);
        csr[p] = (unsigned char)s;
    }
    __syncthreads();

    // ---------------- Phase F: fill padding slots with zero-row index 200 ----------------
    if (t < MG) {
        for (int p = cur[t]; p < roff[t + 1]; ++p) csr[p] = (unsigned char)200;
    }
    __syncthreads();

    const int f32lane = t & 31;
    const int islot   = t >> 5;   // 0..31

    // agg: hcur[d][f] = tanh(dinv[d]*sum_{p} bufX[csr[p]][f] + bias[f]);
    // archOff >= 0: also archive result to global as f16 at column offset archOff.
    auto agg_layer = [&](int archOff) {
        const int fq  = t & 7;
        const int f4  = fq << 2;
        const int dsl = t >> 3;   // 0..127
        for (int d = dsl; d < MG; d += 128) {
            const int p0 = roff[d], p1 = roff[d + 1];
            float a0 = 0.f, a1 = 0.f, a2 = 0.f, a3 = 0.f;
            for (int p = p0; p < p1; p += 4) {
                const unsigned q = *(const unsigned*)(csr + p);
                const float4 v0 = *(const float4*)(bufX + (q & 255u) * 36 + f4);
                const float4 v1 = *(const float4*)(bufX + ((q >> 8) & 255u) * 36 + f4);
                a0 += v0.x; a1 += v0.y; a2 += v0.z; a3 += v0.w;
                a0 += v1.x; a1 += v1.y; a2 += v1.z; a3 += v1.w;
                const float4 v2 = *(const float4*)(bufX + ((q >> 16) & 255u) * 36 + f4);
                const float4 v3 = *(const float4*)(bufX + (q >> 24) * 36 + f4);
                a0 += v2.x; a1 += v2.y; a2 += v2.z; a3 += v2.w;
                a0 += v3.x; a1 += v3.y; a2 += v3.z; a3 += v3.w;
            }
            const float dv = dinv[d];
            const float o0 = tanhf(dv * a0 + bias[f4 + 0]);
            const float o1 = tanhf(dv * a1 + bias[f4 + 1]);
            const float o2 = tanhf(dv * a2 + bias[f4 + 2]);
            const float o3 = tanhf(dv * a3 + bias[f4 + 3]);
            *(float4*)(hcur + d * 36 + f4) = make_float4(o0, o1, o2, o3);
            if (archOff >= 0) {
                const __half2 p01 = __floats2half2_rn(o0, o1);
                const __half2 p23 = __floats2half2_rn(o2, o3);
                __half2* dst = (__half2*)(arch + (size_t)(gbase + d) * 64 + archOff + f4);
                dst[0] = p01;
                dst[1] = p23;
            }
        }
    };

    auto gemm_mid = [&](const float* __restrict__ src) {
        // bufX = (src[200x32] @ W[32x32]) scaled by dinv[row]
        const int f = f32lane;
        {
            float acc0 = 0.f, acc1 = 0.f, acc2 = 0.f, acc3 = 0.f;
            #pragma unroll
            for (int k4 = 0; k4 < 8; ++k4) {
                const float w0 = wreg[k4 * 128 + 0  + f];
                const float w1 = wreg[k4 * 128 + 32 + f];
                const float w2 = wreg[k4 * 128 + 64 + f];
                const float w3 = wreg[k4 * 128 + 96 + f];
                float4 v;
                v = *(const float4*)(src + (islot      ) * 36 + k4 * 4); acc0 += v.x*w0 + v.y*w1 + v.z*w2 + v.w*w3;
                v = *(const float4*)(src + (islot + 32 ) * 36 + k4 * 4); acc1 += v.x*w0 + v.y*w1 + v.z*w2 + v.w*w3;
                v = *(const float4*)(src + (islot + 64 ) * 36 + k4 * 4); acc2 += v.x*w0 + v.y*w1 + v.z*w2 + v.w*w3;
                v = *(const float4*)(src + (islot + 96 ) * 36 + k4 * 4); acc3 += v.x*w0 + v.y*w1 + v.z*w2 + v.w*w3;
            }
            bufX[(islot      ) * 36 + f] = dinv[islot      ] * acc0;
            bufX[(islot + 32 ) * 36 + f] = dinv[islot + 32 ] * acc1;
            bufX[(islot + 64 ) * 36 + f] = dinv[islot + 64 ] * acc2;
            bufX[(islot + 96 ) * 36 + f] = dinv[islot + 96 ] * acc3;
        }
        {
            const int i2  = islot + 192;
            const int i2c = i2 < MG ? i2 : (MG - 1);
            float acc0 = 0.f, acc1 = 0.f, acc2 = 0.f;
            #pragma unroll
            for (int k4 = 0; k4 < 8; ++k4) {
                const float w0 = wreg[k4 * 128 + 0  + f];
                const float w1 = wreg[k4 * 128 + 32 + f];
                const float w2 = wreg[k4 * 128 + 64 + f];
                const float w3 = wreg[k4 * 128 + 96 + f];
                float4 v;
                v = *(const float4*)(src + (islot + 128) * 36 + k4 * 4); acc0 += v.x*w0 + v.y*w1 + v.z*w2 + v.w*w3;
                v = *(const float4*)(src + (islot + 160) * 36 + k4 * 4); acc1 += v.x*w0 + v.y*w1 + v.z*w2 + v.w*w3;
                v = *(const float4*)(src + (i2c        ) * 36 + k4 * 4); acc2 += v.x*w0 + v.y*w1 + v.z*w2 + v.w*w3;
            }
            bufX[(islot + 128) * 36 + f] = dinv[islot + 128] * acc0;
            bufX[(islot + 160) * 36 + f] = dinv[islot + 160] * acc1;
            if (i2 < MG) bufX[i2 * 36 + f] = dinv[i2] * acc2;
        }
    };

    // ---------------- Layer 1 GEMM: x[200x128] @ W1[128x32] ----------------
    // W1 staged in 8KB halves, 3 stagings total. Scalar accumulators only;
    // row group A = islot+{0,32,64,96}, group B = islot+{128,160,192(clamped)}.
    {
        const int f = f32lane;
        const float4* xv = (const float4*)xg;
        // ---- Group A, K-half 1 (wreg = W1 k-rows 0..63 from Phase A) ----
        float a0 = 0.f, a1 = 0.f, a2 = 0.f, a3 = 0.f;
        #pragma unroll 4
        for (int k4 = 0; k4 < 16; ++k4) {
            const float w0 = wreg[k4 * 128 + 0  + f];
            const float w1 = wreg[k4 * 128 + 32 + f];
            const float w2 = wreg[k4 * 128 + 64 + f];
            const float w3 = wreg[k4 * 128 + 96 + f];
            float4 v;
            v = xv[(islot      ) * 32 + k4]; a0 += v.x*w0 + v.y*w1 + v.z*w2 + v.w*w3;
            v = xv[(islot + 32 ) * 32 + k4]; a1 += v.x*w0 + v.y*w1 + v.z*w2 + v.w*w3;
            v = xv[(islot + 64 ) * 32 + k4]; a2 += v.x*w0 + v.y*w1 + v.z*w2 + v.w*w3;
            v = xv[(islot + 96 ) * 32 + k4]; a3 += v.x*w0 + v.y*w1 + v.z*w2 + v.w*w3;
        }
        __syncthreads();
        for (int idx = t; idx < 2048; idx += TPB) wreg[idx] = W1[2048 + idx];
        __syncthreads();
        // ---- Group A, K-half 2 (wreg = W1 k-rows 64..127) ----
        #pragma unroll 4
        for (int k4 = 0; k4 < 16; ++k4) {
            const float w0 = wreg[k4 * 128 + 0  + f];
            const float w1 = wreg[k4 * 128 + 32 + f];
            const float w2 = wreg[k4 * 128 + 64 + f];
            const float w3 = wreg[k4 * 128 + 96 + f];
            float4 v;
            v = xv[(islot      ) * 32 + 16 + k4]; a0 += v.x*w0 + v.y*w1 + v.z*w2 + v.w*w3;
            v = xv[(islot + 32 ) * 32 + 16 + k4]; a1 += v.x*w0 + v.y*w1 + v.z*w2 + v.w*w3;
            v = xv[(islot + 64 ) * 32 + 16 + k4]; a2 += v.x*w0 + v.y*w1 + v.z*w2 + v.w*w3;
            v = xv[(islot + 96 ) * 32 + 16 + k4]; a3 += v.x*w0 + v.y*w1 + v.z*w2 + v.w*w3;
        }
        bufX[(islot      ) * 36 + f] = dinv[islot      ] * a0;
        bufX[(islot + 32 ) * 36 + f] = dinv[islot + 32 ] * a1;
        bufX[(islot + 64 ) * 36 + f] = dinv[islot + 64 ] * a2;
        bufX[(islot + 96 ) * 36 + f] = dinv[islot + 96 ] * a3;
        // ---- Group B, K-half 2 first (wreg already = half 2) ----
        const int r6  = islot + 192;
        const int r6c = (r6 < MG) ? r6 : (MG - 1);
        float b0v = 0.f, b1v = 0.f, b2v = 0.f;
        #pragma unroll 4
        for (int k4 = 0; k4 < 16; ++k4) {
            const float w0 = wreg[k4 * 128 + 0  + f];
            const float w1 = wreg[k4 * 128 + 32 + f];
            const float w2 = wreg[k4 * 128 + 64 + f];
            const float w3 = wreg[k4 * 128 + 96 + f];
            float4 v;
            v = xv[(islot + 128) * 32 + 16 + k4]; b0v += v.x*w0 + v.y*w1 + v.z*w2 + v.w*w3;
            v = xv[(islot + 160) * 32 + 16 + k4]; b1v += v.x*w0 + v.y*w1 + v.z*w2 + v.w*w3;
            v = xv[(r6c        ) * 32 + 16 + k4]; b2v += v.x*w0 + v.y*w1 + v.z*w2 + v.w*w3;
        }
        __syncthreads();
        for (int idx = t; idx < 2048; idx += TPB) wreg[idx] = W1[idx];
        __syncthreads();
        // ---- Group B, K-half 1 ----
        #pragma unroll 4
        for (int k4 = 0; k4 < 16; ++k4) {
            const float w0 = wreg[k4 * 128 + 0  + f];
            const float w1 = wreg[k4 * 128 + 32 + f];
            const float w2 = wreg[k4 * 128 + 64 + f];
            const float w3 = wreg[k4 * 128 + 96 + f];
            float4 v;
            v = xv[(islot + 128) * 32 + k4]; b0v += v.x*w0 + v.y*w1 + v.z*w2 + v.w*w3;
            v = xv[(islot + 160) * 32 + k4]; b1v += v.x*w0 + v.y*w1 + v.z*w2 + v.w*w3;
            v = xv[(r6c        ) * 32 + k4]; b2v += v.x*w0 + v.y*w1 + v.z*w2 + v.w*w3;
        }
        bufX[(islot + 128) * 36 + f] = dinv[islot + 128] * b0v;
        bufX[(islot + 160) * 36 + f] = dinv[islot + 160] * b1v;
        if (r6 < MG) bufX[r6 * 36 + f] = dinv[r6] * b2v;
    }
    __syncthreads();
    agg_layer(0);    // h1 -> arch[:,0:32)
    __syncthreads();

    // ---------------- Layer 2 ----------------
    for (int idx = t; idx < 1024; idx += TPB) wreg[idx] = W2[idx];
    if (t < 32) bias[t] = b2[t];
    __syncthreads();
    gemm_mid(hcur);
    __syncthreads();
    agg_layer(32);   // h2 -> arch[:,32:64)
    __syncthreads();

    // ---------------- Layer 3 ----------------
    for (int idx = t; idx < 1024; idx += TPB) wreg[idx] = W3[idx];
    if (t < 32) bias[t] = b3[t];
    __syncthreads();
    gemm_mid(hcur);
    __syncthreads();
    agg_layer(-1);   // h3 stays in hcur (f32), not archived
    __syncthreads();

    // ---------------- Layer 4 (Fout=1): scl = dinv * (h3 @ W4); scl[200]=0 ----------------
    float* scl = (float*)(smem + OFF_CNT);   // 400 floats available (cnt+cur dead)
    if (t < MG) {
        float a = 0.f;
        #pragma unroll 8
        for (int k = 0; k < 32; ++k) a += hcur[t * 36 + k] * W4[k];
        scl[t] = dinv[t] * a;
    }
    if (t == 512) scl[200] = 0.f;
    __syncthreads();
    if (t < MG) {
        const int p0 = roff[t], p1 = roff[t + 1];
        float s = 0.f;
        for (int p = p0; p < p1; p += 4) {
            const unsigned q = *(const unsigned*)(csr + p);
            s += scl[q & 255u] + scl[(q >> 8) & 255u]
               + scl[(q >> 16) & 255u] + scl[q >> 24];
        }
        h4k[t] = tanhf(dinv[t] * s + b4[0]);
    }
    __syncthreads();

    // ---------------- SortPool: exact stable rank (desc value, asc index) ----------------
    if (t < 512) {
        const int i = t & 255;
        const int half = t >> 8;
        if (i < MG) {
            const float vi = h4k[i];
            int r = 0;
            const int j0 = half * 100, j1 = half * 100 + 100;
            for (int j = j0; j < j1; ++j) {
                const float vj = h4k[j];
                r += (vj > vi || (vj == vi && j < i)) ? 1 : 0;
            }
            atomicAdd(&rank[i], r);
        }
    }
    __syncthreads();
    if (t < MG) {
        const int r = rank[t];
        if (r < 30) ord[r] = t;
    }
    __syncthreads();

    // ---------------- Stage conv weights (bufX tail) + gather top-30 features ----------
    float* topv = bufX;           // [30][100] = 3000 floats
    float* cw   = bufX + 3104;    // cW1: [0,1552)  cW2: [1552,4112); ends at 7216 <= 7236
    for (int idx = t; idx < 1552; idx += TPB) cw[idx] = cW1[idx];
    for (int idx = t; idx < 2560; idx += TPB) cw[1552 + idx] = cW2[idx];
    if (t < 16) bias[t] = cb1[t];
    else if (t < 48) bias[t] = cb2[t - 16];
    for (int idx = t; idx < 2910; idx += TPB) {   // 30*97 grid-stride (R2 bug fixed)
        const int kk = idx / 97;
        const int ff = idx - kk * 97;
        const int nd = ord[kk];
        float v;
        if      (ff < 64) v = __half2float(arch[(size_t)(gbase + nd) * 64 + ff]);
        else if (ff < 96) v = hcur[nd * 36 + (ff - 64)];   // h3, f32
        else              v = h4k[nd];
        topv[kk * 100 + ff] = v;
    }
    __syncthreads();

    // conv scratch in hcur (dead after gather barrier)
    float* c1p2 = hcur;           // [16][30]
    float* c1pl = hcur + 480;     // [16][16]
    float* flat = hcur + 736;     // [352]
    float* hlin = hcur + 1088;    // [128]

    // ---------------- Conv1 (97->16 per slot) + ReLU ----------------
    if (t < 480) {
        const int o  = t & 15;
        const int tt = t >> 4;
        float a = bias[o];
        const float* wrow = cw + o * 97;
        const float* trow = topv + tt * 100;
        #pragma unroll 4
        for (int f = 0; f < 97; ++f) a += wrow[f] * trow[f];
        c1p2[o * 30 + tt] = fmaxf(a, 0.f);
    }
    __syncthreads();

    // ---------------- MaxPool1d(2,2): 30 -> 15 ----------------
    if (t < 240) {
        const int o  = t & 15;
        const int tp = t >> 4;
        c1pl[o * 16 + tp] = fmaxf(c1p2[o * 30 + 2 * tp], c1p2[o * 30 + 2 * tp + 1]);
    }
    __syncthreads();

    // ---------------- Conv2 (16->32, k=5) + ReLU -> flat; init hlin ----------------
    if (t < 352) {
        const int o  = t & 31;
        const int tt = t >> 5;
        float a = bias[16 + o];
        const float* w2r = cw + 1552 + o * 80;
        #pragma unroll
        for (int i2 = 0; i2 < 16; ++i2) {
            #pragma unroll
            for (int kk = 0; kk < 5; ++kk)
                a += w2r[i2 * 5 + kk] * c1pl[i2 * 16 + tt + kk];
        }
        flat[o * 11 + tt] = fmaxf(a, 0.f);
    } else if (t >= 512 && t < 640) {
        hlin[t - 512] = lb1[t - 512];
    }
    __syncthreads();

    // ---------------- Linear 352->128 (split-K over 8 groups) ----------------
    {
        const int f  = t & 127;
        const int kc = t >> 7;
        float a = 0.f;
        const int k0 = kc * 44;
        #pragma unroll 4
        for (int kk = k0; kk < k0 + 44; ++kk) a += flat[kk] * lW1[kk * 128 + f];
        atomicAdd(&hlin[f], a);
    }
    __syncthreads();

    // ---------------- ReLU -> Linear 128->1 -> sigmoid ----------------
    if (t < 128) {
        float p = fmaxf(hlin[t], 0.f) * lW2[t];
        #pragma unroll
        for (int off = 32; off > 0; off >>= 1) p += __shfl_down(p, off);
        if ((t & 63) == 0) red[t >> 6] = p;
    }
    __syncthreads();
    if (t == 0) {
        const float z = red[0] + red[1] + lb2[0];
        out[g] = 1.f / (1.f + expf(-z));
    }
}

extern "C" void kernel_launch(void* const* d_in, const int* in_sizes, int n_in,
                              void* d_out, int out_size, void* d_ws, size_t ws_size,
                              hipStream_t stream) {
    (void)in_sizes; (void)n_in; (void)out_size; (void)ws_size;
    const float* x   = (const float*)d_in[0];
    const int*   ei  = (const int*)d_in[1];
    const float* W1  = (const float*)d_in[3];  const float* b1  = (const float*)d_in[4];
    const float* W2  = (const float*)d_in[5];  const float* b2  = (const float*)d_in[6];
    const float* W3  = (const float*)d_in[7];  const float* b3  = (const float*)d_in[8];
    const float* W4  = (const float*)d_in[9];  const float* b4  = (const float*)d_in[10];
    const float* cW1 = (const float*)d_in[11]; const float* cb1 = (const float*)d_in[12];
    const float* cW2 = (const float*)d_in[13]; const float* cb2 = (const float*)d_in[14];
    const float* lW1 = (const float*)d_in[15]; const float* lb1 = (const float*)d_in[16];
    const float* lW2 = (const float*)d_in[17]; const float* lb2 = (const float*)d_in[18];
    float* out = (float*)d_out;
    __half* arch = (__half*)d_ws;   // needs 512*200*64*2 = 13.1 MB

    hipFuncSetAttribute((const void*)dgcnn_kernel,
                        hipFuncAttributeMaxDynamicSharedMemorySize, SMEM_BYTES);

    dgcnn_kernel<<<GRID, TPB, SMEM_BYTES, stream>>>(
        x, ei, W1, b1, W2, b2, W3, b3, W4, b4,
        cW1, cb1, cW2, cb2, lW1, lb1, lW2, lb2, arch, out);
}

// Round 5
// 327.682 us; speedup vs baseline: 2.1172x; 1.0085x over previous
//
#include <hip/hip_runtime.h>
#include <hip/hip_fp16.h>

// DGCNN forward, fully fused: one workgroup per graph, 2 blocks/CU co-resident.
// f32 everywhere on the sort-key-critical chain; h1/h2 archived to global
// scratch as f16 (conv features only); h3 read back from LDS in f32.
// VGPR discipline: amdgpu_waves_per_eu(8,8) pins the allocator at exactly the
// 64-VGPR/8-wave bucket. R4 regression: launch_bounds(1024,8) made the
// allocator over-shrink to 32 VGPR with ~300 B/thread scratch spill
// (FETCH+WRITE showed ~200 MB of spill traffic). LDS caps us at 2 blocks/CU
// anyway, so anything below 64 VGPR is pure loss.

#define TPB   1024
#define GRID  512
#define MG    200
#define EPG   6400
#define EE    (512 * EPG)

// ---- LDS layout (byte offsets). Total 78,336 B -> 2 blocks/CU (156.7/160 KiB) ----
#define OFF_BUFX 0        // f32[201*36] rows 0..200 (row 200 = zeros); later topv[30][100] + conv W
#define OFF_HCUR 28944    // f32[200*36] current-layer h (f32); later conv scratch
#define OFF_CSR  57744    // u8[7200]    CSR (rows padded to x4 entries, pad -> 200)
#define OFF_ROFF 64944    // i32[201] row offsets (padded units)
#define OFF_CNT  65760    // i32[200] degree counts   \ scl f32[201] aliases CNT..CUR
#define OFF_CUR  66560    // i32[200] cursors         /
#define OFF_DINV 67360    // f32[200]
#define OFF_H4   68160    // f32[200] sort key
#define OFF_RANK 68960    // i32[200]
#define OFF_ORD  69760    // i32[30]
#define OFF_BIAS 69880    // f32[48]
#define OFF_RED  70072    // f32[16] (+8 pad)
#define OFF_WREG 70144    // f32[2048] current weight stage (W1 in 8KB halves)
#define SMEM_BYTES 78336

__global__ __launch_bounds__(TPB)
__attribute__((amdgpu_waves_per_eu(8, 8)))
void dgcnn_kernel(
    const float* __restrict__ x,
    const int*   __restrict__ ei,
    const float* __restrict__ W1, const float* __restrict__ b1,
    const float* __restrict__ W2, const float* __restrict__ b2,
    const float* __restrict__ W3, const float* __restrict__ b3,
    const float* __restrict__ W4, const float* __restrict__ b4,
    const float* __restrict__ cW1, const float* __restrict__ cb1,
    const float* __restrict__ cW2, const float* __restrict__ cb2,
    const float* __restrict__ lW1, const float* __restrict__ lb1,
    const float* __restrict__ lW2, const float* __restrict__ lb2,
    __half* __restrict__ arch,     // [512][200][64] f16 archive of h1|h2
    float* __restrict__ out)
{
    extern __shared__ unsigned char smem[];
    float* bufX = (float*)(smem + OFF_BUFX);
    float* hcur = (float*)(smem + OFF_HCUR);
    unsigned char* csr = (unsigned char*)(smem + OFF_CSR);
    int*   roff = (int*)(smem + OFF_ROFF);
    int*   cnt  = (int*)(smem + OFF_CNT);
    int*   cur  = (int*)(smem + OFF_CUR);
    float* dinv = (float*)(smem + OFF_DINV);
    float* h4k  = (float*)(smem + OFF_H4);
    int*   rank = (int*)(smem + OFF_RANK);
    int*   ord  = (int*)(smem + OFF_ORD);
    float* bias = (float*)(smem + OFF_BIAS);
    float* red  = (float*)(smem + OFF_RED);
    float* wreg = (float*)(smem + OFF_WREG);

    const int g = blockIdx.x;
    const int t = threadIdx.x;
    const int gbase = g * MG;
    const float* xg   = x + (size_t)gbase * 128;
    const int*   srcp = ei + (size_t)g * EPG;
    const int*   dstp = ei + (size_t)EE + (size_t)g * EPG;

    // ---------------- Phase A: stage W1 half 1, zero counters + zero row ----------------
    for (int idx = t; idx < 2048; idx += TPB) wreg[idx] = W1[idx];
    if (t < 32) bias[t] = b1[t];
    if (t < MG) { cnt[t] = 0; rank[t] = 0; }
    if (t >= 512 && t < 548) bufX[200 * 36 + (t - 512)] = 0.f;   // zero row 200
    __syncthreads();

    // ---------------- Phase B: in-degree count ----------------
    for (int e = t; e < EPG; e += TPB) atomicAdd(&cnt[dstp[e] - gbase], 1);
    __syncthreads();

    // ---------------- Phase C: dinv + prefix scan over PADDED row lengths ----------------
    if (t >= 256 && t < 256 + MG) {
        int i = t - 256;
        dinv[i] = 1.0f / sqrtf((float)(cnt[i] + 1));
    }
    if (t < 64) {
        if (t == 0) roff[0] = 0;
        int carry = 0;
        #pragma unroll
        for (int c = 0; c < 4; ++c) {
            const int i = c * 64 + t;
            int v = (i < MG) ? ((cnt[i] + 4) & ~3) : 0;   // self-loop +1, pad to x4
            #pragma unroll
            for (int off = 1; off < 64; off <<= 1) {
                int u = __shfl_up(v, off);
                if (t >= (int)off) v += u;
            }
            if (i < MG) roff[i + 1] = carry + v;
            carry += __shfl(v, 63);
        }
    }
    __syncthreads();

    // ---------------- Phase D: self-loop entry + cursors ----------------
    if (t < MG) {
        int p = roff[t];
        csr[p] = (unsigned char)t;
        cur[t] = p + 1;
    }
    __syncthreads();

    // ---------------- Phase E: CSR placement ----------------
    for (int e = t; e < EPG; e += TPB) {
        int d = dstp[e] - gbase;
        int s = srcp[e] - gbase;
        int p = atomicAdd(&cur[d], 1);
        csr[p] = (unsigned char)s;
    }
    __syncthreads();

    // ---------------- Phase F: fill padding slots with zero-row index 200 ----------------
    if (t < MG) {
        for (int p = cur[t]; p < roff[t + 1]; ++p) csr[p] = (unsigned char)200;
    }
    __syncthreads();

    const int f32lane = t & 31;
    const int islot   = t >> 5;   // 0..31

    // agg: hcur[d][f] = tanh(dinv[d]*sum_{p} bufX[csr[p]][f] + bias[f]);
    // archOff >= 0: also archive result to global as f16 at column offset archOff.
    auto agg_layer = [&](int archOff) {
        const int fq  = t & 7;
        const int f4  = fq << 2;
        const int dsl = t >> 3;   // 0..127
        for (int d = dsl; d < MG; d += 128) {
            const int p0 = roff[d], p1 = roff[d + 1];
            float a0 = 0.f, a1 = 0.f, a2 = 0.f, a3 = 0.f;
            for (int p = p0; p < p1; p += 4) {
                const unsigned q = *(const unsigned*)(csr + p);
                const float4 v0 = *(const float4*)(bufX + (q & 255u) * 36 + f4);
                const float4 v1 = *(const float4*)(bufX + ((q >> 8) & 255u) * 36 + f4);
                a0 += v0.x; a1 += v0.y; a2 += v0.z; a3 += v0.w;
                a0 += v1.x; a1 += v1.y; a2 += v1.z; a3 += v1.w;
                const float4 v2 = *(const float4*)(bufX + ((q >> 16) & 255u) * 36 + f4);
                const float4 v3 = *(const float4*)(bufX + (q >> 24) * 36 + f4);
                a0 += v2.x; a1 += v2.y; a2 += v2.z; a3 += v2.w;
                a0 += v3.x; a1 += v3.y; a2 += v3.z; a3 += v3.w;
            }
            const float dv = dinv[d];
            const float o0 = tanhf(dv * a0 + bias[f4 + 0]);
            const float o1 = tanhf(dv * a1 + bias[f4 + 1]);
            const float o2 = tanhf(dv * a2 + bias[f4 + 2]);
            const float o3 = tanhf(dv * a3 + bias[f4 + 3]);
            *(float4*)(hcur + d * 36 + f4) = make_float4(o0, o1, o2, o3);
            if (archOff >= 0) {
                const __half2 p01 = __floats2half2_rn(o0, o1);
                const __half2 p23 = __floats2half2_rn(o2, o3);
                __half2* dst = (__half2*)(arch + (size_t)(gbase + d) * 64 + archOff + f4);
                dst[0] = p01;
                dst[1] = p23;
            }
        }
    };

    auto gemm_mid = [&](const float* __restrict__ src) {
        // bufX = (src[200x32] @ W[32x32]) scaled by dinv[row]
        const int f = f32lane;
        {
            float acc0 = 0.f, acc1 = 0.f, acc2 = 0.f, acc3 = 0.f;
            #pragma unroll
            for (int k4 = 0; k4 < 8; ++k4) {
                const float w0 = wreg[k4 * 128 + 0  + f];
                const float w1 = wreg[k4 * 128 + 32 + f];
                const float w2 = wreg[k4 * 128 + 64 + f];
                const float w3 = wreg[k4 * 128 + 96 + f];
                float4 v;
                v = *(const float4*)(src + (islot      ) * 36 + k4 * 4); acc0 += v.x*w0 + v.y*w1 + v.z*w2 + v.w*w3;
                v = *(const float4*)(src + (islot + 32 ) * 36 + k4 * 4); acc1 += v.x*w0 + v.y*w1 + v.z*w2 + v.w*w3;
                v = *(const float4*)(src + (islot + 64 ) * 36 + k4 * 4); acc2 += v.x*w0 + v.y*w1 + v.z*w2 + v.w*w3;
                v = *(const float4*)(src + (islot + 96 ) * 36 + k4 * 4); acc3 += v.x*w0 + v.y*w1 + v.z*w2 + v.w*w3;
            }
            bufX[(islot      ) * 36 + f] = dinv[islot      ] * acc0;
            bufX[(islot + 32 ) * 36 + f] = dinv[islot + 32 ] * acc1;
            bufX[(islot + 64 ) * 36 + f] = dinv[islot + 64 ] * acc2;
            bufX[(islot + 96 ) * 36 + f] = dinv[islot + 96 ] * acc3;
        }
        {
            const int i2  = islot + 192;
            const int i2c = i2 < MG ? i2 : (MG - 1);
            float acc0 = 0.f, acc1 = 0.f, acc2 = 0.f;
            #pragma unroll
            for (int k4 = 0; k4 < 8; ++k4) {
                const float w0 = wreg[k4 * 128 + 0  + f];
                const float w1 = wreg[k4 * 128 + 32 + f];
                const float w2 = wreg[k4 * 128 + 64 + f];
                const float w3 = wreg[k4 * 128 + 96 + f];
                float4 v;
                v = *(const float4*)(src + (islot + 128) * 36 + k4 * 4); acc0 += v.x*w0 + v.y*w1 + v.z*w2 + v.w*w3;
                v = *(const float4*)(src + (islot + 160) * 36 + k4 * 4); acc1 += v.x*w0 + v.y*w1 + v.z*w2 + v.w*w3;
                v = *(const float4*)(src + (i2c        ) * 36 + k4 * 4); acc2 += v.x*w0 + v.y*w1 + v.z*w2 + v.w*w3;
            }
            bufX[(islot + 128) * 36 + f] = dinv[islot + 128] * acc0;
            bufX[(islot + 160) * 36 + f] = dinv[islot + 160] * acc1;
            if (i2 < MG) bufX[i2 * 36 + f] = dinv[i2] * acc2;
        }
    };

    // ---------------- Layer 1 GEMM: x[200x128] @ W1[128x32] ----------------
    // W1 staged in 8KB halves, 3 stagings total. Scalar accumulators only;
    // row group A = islot+{0,32,64,96}, group B = islot+{128,160,192(clamped)}.
    {
        const int f = f32lane;
        const float4* xv = (const float4*)xg;
        // ---- Group A, K-half 1 (wreg = W1 k-rows 0..63 from Phase A) ----
        float a0 = 0.f, a1 = 0.f, a2 = 0.f, a3 = 0.f;
        #pragma unroll 4
        for (int k4 = 0; k4 < 16; ++k4) {
            const float w0 = wreg[k4 * 128 + 0  + f];
            const float w1 = wreg[k4 * 128 + 32 + f];
            const float w2 = wreg[k4 * 128 + 64 + f];
            const float w3 = wreg[k4 * 128 + 96 + f];
            float4 v;
            v = xv[(islot      ) * 32 + k4]; a0 += v.x*w0 + v.y*w1 + v.z*w2 + v.w*w3;
            v = xv[(islot + 32 ) * 32 + k4]; a1 += v.x*w0 + v.y*w1 + v.z*w2 + v.w*w3;
            v = xv[(islot + 64 ) * 32 + k4]; a2 += v.x*w0 + v.y*w1 + v.z*w2 + v.w*w3;
            v = xv[(islot + 96 ) * 32 + k4]; a3 += v.x*w0 + v.y*w1 + v.z*w2 + v.w*w3;
        }
        __syncthreads();
        for (int idx = t; idx < 2048; idx += TPB) wreg[idx] = W1[2048 + idx];
        __syncthreads();
        // ---- Group A, K-half 2 (wreg = W1 k-rows 64..127) ----
        #pragma unroll 4
        for (int k4 = 0; k4 < 16; ++k4) {
            const float w0 = wreg[k4 * 128 + 0  + f];
            const float w1 = wreg[k4 * 128 + 32 + f];
            const float w2 = wreg[k4 * 128 + 64 + f];
            const float w3 = wreg[k4 * 128 + 96 + f];
            float4 v;
            v = xv[(islot      ) * 32 + 16 + k4]; a0 += v.x*w0 + v.y*w1 + v.z*w2 + v.w*w3;
            v = xv[(islot + 32 ) * 32 + 16 + k4]; a1 += v.x*w0 + v.y*w1 + v.z*w2 + v.w*w3;
            v = xv[(islot + 64 ) * 32 + 16 + k4]; a2 += v.x*w0 + v.y*w1 + v.z*w2 + v.w*w3;
            v = xv[(islot + 96 ) * 32 + 16 + k4]; a3 += v.x*w0 + v.y*w1 + v.z*w2 + v.w*w3;
        }
        bufX[(islot      ) * 36 + f] = dinv[islot      ] * a0;
        bufX[(islot + 32 ) * 36 + f] = dinv[islot + 32 ] * a1;
        bufX[(islot + 64 ) * 36 + f] = dinv[islot + 64 ] * a2;
        bufX[(islot + 96 ) * 36 + f] = dinv[islot + 96 ] * a3;
        // ---- Group B, K-half 2 first (wreg already = half 2) ----
        const int r6  = islot + 192;
        const int r6c = (r6 < MG) ? r6 : (MG - 1);
        float b0v = 0.f, b1v = 0.f, b2v = 0.f;
        #pragma unroll 4
        for (int k4 = 0; k4 < 16; ++k4) {
            const float w0 = wreg[k4 * 128 + 0  + f];
            const float w1 = wreg[k4 * 128 + 32 + f];
            const float w2 = wreg[k4 * 128 + 64 + f];
            const float w3 = wreg[k4 * 128 + 96 + f];
            float4 v;
            v = xv[(islot + 128) * 32 + 16 + k4]; b0v += v.x*w0 + v.y*w1 + v.z*w2 + v.w*w3;
            v = xv[(islot + 160) * 32 + 16 + k4]; b1v += v.x*w0 + v.y*w1 + v.z*w2 + v.w*w3;
            v = xv[(r6c        ) * 32 + 16 + k4]; b2v += v.x*w0 + v.y*w1 + v.z*w2 + v.w*w3;
        }
        __syncthreads();
        for (int idx = t; idx < 2048; idx += TPB) wreg[idx] = W1[idx];
        __syncthreads();
        // ---- Group B, K-half 1 ----
        #pragma unroll 4
        for (int k4 = 0; k4 < 16; ++k4) {
            const float w0 = wreg[k4 * 128 + 0  + f];
            const float w1 = wreg[k4 * 128 + 32 + f];
            const float w2 = wreg[k4 * 128 + 64 + f];
            const float w3 = wreg[k4 * 128 + 96 + f];
            float4 v;
            v = xv[(islot + 128) * 32 + k4]; b0v += v.x*w0 + v.y*w1 + v.z*w2 + v.w*w3;
            v = xv[(islot + 160) * 32 + k4]; b1v += v.x*w0 + v.y*w1 + v.z*w2 + v.w*w3;
            v = xv[(r6c        ) * 32 + k4]; b2v += v.x*w0 + v.y*w1 + v.z*w2 + v.w*w3;
        }
        bufX[(islot + 128) * 36 + f] = dinv[islot + 128] * b0v;
        bufX[(islot + 160) * 36 + f] = dinv[islot + 160] * b1v;
        if (r6 < MG) bufX[r6 * 36 + f] = dinv[r6] * b2v;
    }
    __syncthreads();
    agg_layer(0);    // h1 -> arch[:,0:32)
    __syncthreads();

    // ---------------- Layer 2 ----------------
    for (int idx = t; idx < 1024; idx += TPB) wreg[idx] = W2[idx];
    if (t < 32) bias[t] = b2[t];
    __syncthreads();
    gemm_mid(hcur);
    __syncthreads();
    agg_layer(32);   // h2 -> arch[:,32:64)
    __syncthreads();

    // ---------------- Layer 3 ----------------
    for (int idx = t; idx < 1024; idx += TPB) wreg[idx] = W3[idx];
    if (t < 32) bias[t] = b3[t];
    __syncthreads();
    gemm_mid(hcur);
    __syncthreads();
    agg_layer(-1);   // h3 stays in hcur (f32), not archived
    __syncthreads();

    // ---------------- Layer 4 (Fout=1): scl = dinv * (h3 @ W4); scl[200]=0 ----------------
    float* scl = (float*)(smem + OFF_CNT);   // 400 floats available (cnt+cur dead)
    if (t < MG) {
        float a = 0.f;
        #pragma unroll 8
        for (int k = 0; k < 32; ++k) a += hcur[t * 36 + k] * W4[k];
        scl[t] = dinv[t] * a;
    }
    if (t == 512) scl[200] = 0.f;
    __syncthreads();
    if (t < MG) {
        const int p0 = roff[t], p1 = roff[t + 1];
        float s = 0.f;
        for (int p = p0; p < p1; p += 4) {
            const unsigned q = *(const unsigned*)(csr + p);
            s += scl[q & 255u] + scl[(q >> 8) & 255u]
               + scl[(q >> 16) & 255u] + scl[q >> 24];
        }
        h4k[t] = tanhf(dinv[t] * s + b4[0]);
    }
    __syncthreads();

    // ---------------- SortPool: exact stable rank (desc value, asc index) ----------------
    if (t < 512) {
        const int i = t & 255;
        const int half = t >> 8;
        if (i < MG) {
            const float vi = h4k[i];
            int r = 0;
            const int j0 = half * 100, j1 = half * 100 + 100;
            for (int j = j0; j < j1; ++j) {
                const float vj = h4k[j];
                r += (vj > vi || (vj == vi && j < i)) ? 1 : 0;
            }
            atomicAdd(&rank[i], r);
        }
    }
    __syncthreads();
    if (t < MG) {
        const int r = rank[t];
        if (r < 30) ord[r] = t;
    }
    __syncthreads();

    // ---------------- Stage conv weights (bufX tail) + gather top-30 features ----------
    float* topv = bufX;           // [30][100] = 3000 floats
    float* cw   = bufX + 3104;    // cW1: [0,1552)  cW2: [1552,4112); ends at 7216 <= 7236
    for (int idx = t; idx < 1552; idx += TPB) cw[idx] = cW1[idx];
    for (int idx = t; idx < 2560; idx += TPB) cw[1552 + idx] = cW2[idx];
    if (t < 16) bias[t] = cb1[t];
    else if (t < 48) bias[t] = cb2[t - 16];
    for (int idx = t; idx < 2910; idx += TPB) {   // 30*97 grid-stride
        const int kk = idx / 97;
        const int ff = idx - kk * 97;
        const int nd = ord[kk];
        float v;
        if      (ff < 64) v = __half2float(arch[(size_t)(gbase + nd) * 64 + ff]);
        else if (ff < 96) v = hcur[nd * 36 + (ff - 64)];   // h3, f32
        else              v = h4k[nd];
        topv[kk * 100 + ff] = v;
    }
    __syncthreads();

    // conv scratch in hcur (dead after gather barrier)
    float* c1p2 = hcur;           // [16][30]
    float* c1pl = hcur + 480;     // [16][16]
    float* flat = hcur + 736;     // [352]
    float* hlin = hcur + 1088;    // [128]

    // ---------------- Conv1 (97->16 per slot) + ReLU ----------------
    if (t < 480) {
        const int o  = t & 15;
        const int tt = t >> 4;
        float a = bias[o];
        const float* wrow = cw + o * 97;
        const float* trow = topv + tt * 100;
        #pragma unroll 4
        for (int f = 0; f < 97; ++f) a += wrow[f] * trow[f];
        c1p2[o * 30 + tt] = fmaxf(a, 0.f);
    }
    __syncthreads();

    // ---------------- MaxPool1d(2,2): 30 -> 15 ----------------
    if (t < 240) {
        const int o  = t & 15;
        const int tp = t >> 4;
        c1pl[o * 16 + tp] = fmaxf(c1p2[o * 30 + 2 * tp], c1p2[o * 30 + 2 * tp + 1]);
    }
    __syncthreads();

    // ---------------- Conv2 (16->32, k=5) + ReLU -> flat; init hlin ----------------
    if (t < 352) {
        const int o  = t & 31;
        const int tt = t >> 5;
        float a = bias[16 + o];
        const float* w2r = cw + 1552 + o * 80;
        #pragma unroll
        for (int i2 = 0; i2 < 16; ++i2) {
            #pragma unroll
            for (int kk = 0; kk < 5; ++kk)
                a += w2r[i2 * 5 + kk] * c1pl[i2 * 16 + tt + kk];
        }
        flat[o * 11 + tt] = fmaxf(a, 0.f);
    } else if (t >= 512 && t < 640) {
        hlin[t - 512] = lb1[t - 512];
    }
    __syncthreads();

    // ---------------- Linear 352->128 (split-K over 8 groups) ----------------
    {
        const int f  = t & 127;
        const int kc = t >> 7;
        float a = 0.f;
        const int k0 = kc * 44;
        #pragma unroll 4
        for (int kk = k0; kk < k0 + 44; ++kk) a += flat[kk] * lW1[kk * 128 + f];
        atomicAdd(&hlin[f], a);
    }
    __syncthreads();

    // ---------------- ReLU -> Linear 128->1 -> sigmoid ----------------
    if (t < 128) {
        float p = fmaxf(hlin[t], 0.f) * lW2[t];
        #pragma unroll
        for (int off = 32; off > 0; off >>= 1) p += __shfl_down(p, off);
        if ((t & 63) == 0) red[t >> 6] = p;
    }
    __syncthreads();
    if (t == 0) {
        const float z = red[0] + red[1] + lb2[0];
        out[g] = 1.f / (1.f + expf(-z));
    }
}

extern "C" void kernel_launch(void* const* d_in, const int* in_sizes, int n_in,
                              void* d_out, int out_size, void* d_ws, size_t ws_size,
                              hipStream_t stream) {
    (void)in_sizes; (void)n_in; (void)out_size; (void)ws_size;
    const float* x   = (const float*)d_in[0];
    const int*   ei  = (const int*)d_in[1];
    const float* W1  = (const float*)d_in[3];  const float* b1  = (const float*)d_in[4];
    const float* W2  = (const float*)d_in[5];  const float* b2  = (const float*)d_in[6];
    const float* W3  = (const float*)d_in[7];  const float* b3  = (const float*)d_in[8];
    const float* W4  = (const float*)d_in[9];  const float* b4  = (const float*)d_in[10];
    const float* cW1 = (const float*)d_in[11]; const float* cb1 = (const float*)d_in[12];
    const float* cW2 = (const float*)d_in[13]; const float* cb2 = (const float*)d_in[14];
    const float* lW1 = (const float*)d_in[15]; const float* lb1 = (const float*)d_in[16];
    const float* lW2 = (const float*)d_in[17]; const float* lb2 = (const float*)d_in[18];
    float* out = (float*)d_out;
    __half* arch = (__half*)d_ws;   // needs 512*200*64*2 = 13.1 MB

    hipFuncSetAttribute((const void*)dgcnn_kernel,
                        hipFuncAttributeMaxDynamicSharedMemorySize, SMEM_BYTES);

    dgcnn_kernel<<<GRID, TPB, SMEM_BYTES, stream>>>(
        x, ei, W1, b1, W2, b2, W3, b3, W4, b4,
        cW1, cb1, cW2, cb2, lW1, lb1, lW2, lb2, arch, out);
}

// Round 6
// 281.419 us; speedup vs baseline: 2.4653x; 1.1644x over previous
//
#include <hip/hip_runtime.h>
#include <hip/hip_fp16.h>

// DGCNN forward, fully fused: one workgroup per graph, target 2 blocks/CU.
// f32 everywhere on the sort-key-critical chain; h1/h2 archived to global
// scratch as f16 (conv features only); h3 read back from LDS in f32.
//
// VGPR discipline (hard-won): do NOT pass any occupancy hint. Every explicit
// hint tried (launch_bounds(1024,8) in R3/R4, amdgpu_waves_per_eu(8,8) in R5)
// pinned the allocator at 32 arch-VGPRs with ~200 MB/launch scratch spill
// traffic (FETCH 123 MB / WRITE 169 MB vs ~90/14 ideal) and dur ~221 us.
// Plain __launch_bounds__(1024) (R1) allocated 60 VGPR, zero spill.
// 60 <= 64 keeps 8 waves/EU -> 2 blocks/CU with our 78 KB LDS.

#define TPB   1024
#define GRID  512
#define MG    200
#define EPG   6400
#define EE    (512 * EPG)

// ---- LDS layout (byte offsets). Total 78,336 B -> 2 blocks/CU (156.7/160 KiB) ----
#define OFF_BUFX 0        // f32[201*36] rows 0..200 (row 200 = zeros); later topv[30][100] + conv W
#define OFF_HCUR 28944    // f32[200*36] current-layer h (f32); later conv scratch
#define OFF_CSR  57744    // u8[7200]    CSR (rows padded to x4 entries, pad -> 200)
#define OFF_ROFF 64944    // i32[201] row offsets (padded units)
#define OFF_CNT  65760    // i32[200] degree counts   \ scl f32[201] aliases CNT..CUR
#define OFF_CUR  66560    // i32[200] cursors         /
#define OFF_DINV 67360    // f32[200]
#define OFF_H4   68160    // f32[200] sort key
#define OFF_RANK 68960    // i32[200]
#define OFF_ORD  69760    // i32[30]
#define OFF_BIAS 69880    // f32[48]
#define OFF_RED  70072    // f32[16] (+8 pad)
#define OFF_WREG 70144    // f32[2048] current weight stage (W1 in 8KB halves)
#define SMEM_BYTES 78336

__global__ __launch_bounds__(TPB)
void dgcnn_kernel(
    const float* __restrict__ x,
    const int*   __restrict__ ei,
    const float* __restrict__ W1, const float* __restrict__ b1,
    const float* __restrict__ W2, const float* __restrict__ b2,
    const float* __restrict__ W3, const float* __restrict__ b3,
    const float* __restrict__ W4, const float* __restrict__ b4,
    const float* __restrict__ cW1, const float* __restrict__ cb1,
    const float* __restrict__ cW2, const float* __restrict__ cb2,
    const float* __restrict__ lW1, const float* __restrict__ lb1,
    const float* __restrict__ lW2, const float* __restrict__ lb2,
    __half* __restrict__ arch,     // [512][200][64] f16 archive of h1|h2
    float* __restrict__ out)
{
    extern __shared__ unsigned char smem[];
    float* bufX = (float*)(smem + OFF_BUFX);
    float* hcur = (float*)(smem + OFF_HCUR);
    unsigned char* csr = (unsigned char*)(smem + OFF_CSR);
    int*   roff = (int*)(smem + OFF_ROFF);
    int*   cnt  = (int*)(smem + OFF_CNT);
    int*   cur  = (int*)(smem + OFF_CUR);
    float* dinv = (float*)(smem + OFF_DINV);
    float* h4k  = (float*)(smem + OFF_H4);
    int*   rank = (int*)(smem + OFF_RANK);
    int*   ord  = (int*)(smem + OFF_ORD);
    float* bias = (float*)(smem + OFF_BIAS);
    float* red  = (float*)(smem + OFF_RED);
    float* wreg = (float*)(smem + OFF_WREG);

    const int g = blockIdx.x;
    const int t = threadIdx.x;
    const int gbase = g * MG;
    const float* xg   = x + (size_t)gbase * 128;
    const int*   srcp = ei + (size_t)g * EPG;
    const int*   dstp = ei + (size_t)EE + (size_t)g * EPG;

    // ---------------- Phase A: stage W1 half 1, zero counters + zero row ----------------
    for (int idx = t; idx < 2048; idx += TPB) wreg[idx] = W1[idx];
    if (t < 32) bias[t] = b1[t];
    if (t < MG) { cnt[t] = 0; rank[t] = 0; }
    if (t >= 512 && t < 548) bufX[200 * 36 + (t - 512)] = 0.f;   // zero row 200
    __syncthreads();

    // ---------------- Phase B: in-degree count ----------------
    for (int e = t; e < EPG; e += TPB) atomicAdd(&cnt[dstp[e] - gbase], 1);
    __syncthreads();

    // ---------------- Phase C: dinv + prefix scan over PADDED row lengths ----------------
    if (t >= 256 && t < 256 + MG) {
        int i = t - 256;
        dinv[i] = 1.0f / sqrtf((float)(cnt[i] + 1));
    }
    if (t < 64) {
        if (t == 0) roff[0] = 0;
        int carry = 0;
        #pragma unroll
        for (int c = 0; c < 4; ++c) {
            const int i = c * 64 + t;
            int v = (i < MG) ? ((cnt[i] + 4) & ~3) : 0;   // self-loop +1, pad to x4
            #pragma unroll
            for (int off = 1; off < 64; off <<= 1) {
                int u = __shfl_up(v, off);
                if (t >= (int)off) v += u;
            }
            if (i < MG) roff[i + 1] = carry + v;
            carry += __shfl(v, 63);
        }
    }
    __syncthreads();

    // ---------------- Phase D: self-loop entry + cursors ----------------
    if (t < MG) {
        int p = roff[t];
        csr[p] = (unsigned char)t;
        cur[t] = p + 1;
    }
    __syncthreads();

    // ---------------- Phase E: CSR placement ----------------
    for (int e = t; e < EPG; e += TPB) {
        int d = dstp[e] - gbase;
        int s = srcp[e] - gbase;
        int p = atomicAdd(&cur[d], 1);
        csr[p] = (unsigned char)s;
    }
    __syncthreads();

    // ---------------- Phase F: fill padding slots with zero-row index 200 ----------------
    if (t < MG) {
        for (int p = cur[t]; p < roff[t + 1]; ++p) csr[p] = (unsigned char)200;
    }
    __syncthreads();

    const int f32lane = t & 31;
    const int islot   = t >> 5;   // 0..31

    // agg: hcur[d][f] = tanh(dinv[d]*sum_{p} bufX[csr[p]][f] + bias[f]);
    // archOff >= 0: also archive result to global as f16 at column offset archOff.
    auto agg_layer = [&](int archOff) {
        const int fq  = t & 7;
        const int f4  = fq << 2;
        const int dsl = t >> 3;   // 0..127
        for (int d = dsl; d < MG; d += 128) {
            const int p0 = roff[d], p1 = roff[d + 1];
            float a0 = 0.f, a1 = 0.f, a2 = 0.f, a3 = 0.f;
            for (int p = p0; p < p1; p += 4) {
                const unsigned q = *(const unsigned*)(csr + p);
                const float4 v0 = *(const float4*)(bufX + (q & 255u) * 36 + f4);
                const float4 v1 = *(const float4*)(bufX + ((q >> 8) & 255u) * 36 + f4);
                a0 += v0.x; a1 += v0.y; a2 += v0.z; a3 += v0.w;
                a0 += v1.x; a1 += v1.y; a2 += v1.z; a3 += v1.w;
                const float4 v2 = *(const float4*)(bufX + ((q >> 16) & 255u) * 36 + f4);
                const float4 v3 = *(const float4*)(bufX + (q >> 24) * 36 + f4);
                a0 += v2.x; a1 += v2.y; a2 += v2.z; a3 += v2.w;
                a0 += v3.x; a1 += v3.y; a2 += v3.z; a3 += v3.w;
            }
            const float dv = dinv[d];
            const float o0 = tanhf(dv * a0 + bias[f4 + 0]);
            const float o1 = tanhf(dv * a1 + bias[f4 + 1]);
            const float o2 = tanhf(dv * a2 + bias[f4 + 2]);
            const float o3 = tanhf(dv * a3 + bias[f4 + 3]);
            *(float4*)(hcur + d * 36 + f4) = make_float4(o0, o1, o2, o3);
            if (archOff >= 0) {
                const __half2 p01 = __floats2half2_rn(o0, o1);
                const __half2 p23 = __floats2half2_rn(o2, o3);
                __half2* dst = (__half2*)(arch + (size_t)(gbase + d) * 64 + archOff + f4);
                dst[0] = p01;
                dst[1] = p23;
            }
        }
    };

    auto gemm_mid = [&](const float* __restrict__ src) {
        // bufX = (src[200x32] @ W[32x32]) scaled by dinv[row]
        const int f = f32lane;
        {
            float acc0 = 0.f, acc1 = 0.f, acc2 = 0.f, acc3 = 0.f;
            #pragma unroll 2
            for (int k4 = 0; k4 < 8; ++k4) {
                const float w0 = wreg[k4 * 128 + 0  + f];
                const float w1 = wreg[k4 * 128 + 32 + f];
                const float w2 = wreg[k4 * 128 + 64 + f];
                const float w3 = wreg[k4 * 128 + 96 + f];
                float4 v;
                v = *(const float4*)(src + (islot      ) * 36 + k4 * 4); acc0 += v.x*w0 + v.y*w1 + v.z*w2 + v.w*w3;
                v = *(const float4*)(src + (islot + 32 ) * 36 + k4 * 4); acc1 += v.x*w0 + v.y*w1 + v.z*w2 + v.w*w3;
                v = *(const float4*)(src + (islot + 64 ) * 36 + k4 * 4); acc2 += v.x*w0 + v.y*w1 + v.z*w2 + v.w*w3;
                v = *(const float4*)(src + (islot + 96 ) * 36 + k4 * 4); acc3 += v.x*w0 + v.y*w1 + v.z*w2 + v.w*w3;
            }
            bufX[(islot      ) * 36 + f] = dinv[islot      ] * acc0;
            bufX[(islot + 32 ) * 36 + f] = dinv[islot + 32 ] * acc1;
            bufX[(islot + 64 ) * 36 + f] = dinv[islot + 64 ] * acc2;
            bufX[(islot + 96 ) * 36 + f] = dinv[islot + 96 ] * acc3;
        }
        {
            const int i2  = islot + 192;
            const int i2c = i2 < MG ? i2 : (MG - 1);
            float acc0 = 0.f, acc1 = 0.f, acc2 = 0.f;
            #pragma unroll 2
            for (int k4 = 0; k4 < 8; ++k4) {
                const float w0 = wreg[k4 * 128 + 0  + f];
                const float w1 = wreg[k4 * 128 + 32 + f];
                const float w2 = wreg[k4 * 128 + 64 + f];
                const float w3 = wreg[k4 * 128 + 96 + f];
                float4 v;
                v = *(const float4*)(src + (islot + 128) * 36 + k4 * 4); acc0 += v.x*w0 + v.y*w1 + v.z*w2 + v.w*w3;
                v = *(const float4*)(src + (islot + 160) * 36 + k4 * 4); acc1 += v.x*w0 + v.y*w1 + v.z*w2 + v.w*w3;
                v = *(const float4*)(src + (i2c        ) * 36 + k4 * 4); acc2 += v.x*w0 + v.y*w1 + v.z*w2 + v.w*w3;
            }
            bufX[(islot + 128) * 36 + f] = dinv[islot + 128] * acc0;
            bufX[(islot + 160) * 36 + f] = dinv[islot + 160] * acc1;
            if (i2 < MG) bufX[i2 * 36 + f] = dinv[i2] * acc2;
        }
    };

    // ---------------- Layer 1 GEMM: x[200x128] @ W1[128x32] ----------------
    // W1 staged in 8KB halves, 3 stagings total. Scalar accumulators only;
    // row group A = islot+{0,32,64,96}, group B = islot+{128,160,192(clamped)}.
    // unroll 2 (not 4): keeps the live-value window small so the unconstrained
    // allocator lands <= 64 VGPR (2 blocks/CU).
    {
        const int f = f32lane;
        const float4* xv = (const float4*)xg;
        // ---- Group A, K-half 1 (wreg = W1 k-rows 0..63 from Phase A) ----
        float a0 = 0.f, a1 = 0.f, a2 = 0.f, a3 = 0.f;
        #pragma unroll 2
        for (int k4 = 0; k4 < 16; ++k4) {
            const float w0 = wreg[k4 * 128 + 0  + f];
            const float w1 = wreg[k4 * 128 + 32 + f];
            const float w2 = wreg[k4 * 128 + 64 + f];
            const float w3 = wreg[k4 * 128 + 96 + f];
            float4 v;
            v = xv[(islot      ) * 32 + k4]; a0 += v.x*w0 + v.y*w1 + v.z*w2 + v.w*w3;
            v = xv[(islot + 32 ) * 32 + k4]; a1 += v.x*w0 + v.y*w1 + v.z*w2 + v.w*w3;
            v = xv[(islot + 64 ) * 32 + k4]; a2 += v.x*w0 + v.y*w1 + v.z*w2 + v.w*w3;
            v = xv[(islot + 96 ) * 32 + k4]; a3 += v.x*w0 + v.y*w1 + v.z*w2 + v.w*w3;
        }
        __syncthreads();
        for (int idx = t; idx < 2048; idx += TPB) wreg[idx] = W1[2048 + idx];
        __syncthreads();
        // ---- Group A, K-half 2 (wreg = W1 k-rows 64..127) ----
        #pragma unroll 2
        for (int k4 = 0; k4 < 16; ++k4) {
            const float w0 = wreg[k4 * 128 + 0  + f];
            const float w1 = wreg[k4 * 128 + 32 + f];
            const float w2 = wreg[k4 * 128 + 64 + f];
            const float w3 = wreg[k4 * 128 + 96 + f];
            float4 v;
            v = xv[(islot      ) * 32 + 16 + k4]; a0 += v.x*w0 + v.y*w1 + v.z*w2 + v.w*w3;
            v = xv[(islot + 32 ) * 32 + 16 + k4]; a1 += v.x*w0 + v.y*w1 + v.z*w2 + v.w*w3;
            v = xv[(islot + 64 ) * 32 + 16 + k4]; a2 += v.x*w0 + v.y*w1 + v.z*w2 + v.w*w3;
            v = xv[(islot + 96 ) * 32 + 16 + k4]; a3 += v.x*w0 + v.y*w1 + v.z*w2 + v.w*w3;
        }
        bufX[(islot      ) * 36 + f] = dinv[islot      ] * a0;
        bufX[(islot + 32 ) * 36 + f] = dinv[islot + 32 ] * a1;
        bufX[(islot + 64 ) * 36 + f] = dinv[islot + 64 ] * a2;
        bufX[(islot + 96 ) * 36 + f] = dinv[islot + 96 ] * a3;
        // ---- Group B, K-half 2 first (wreg already = half 2) ----
        const int r6  = islot + 192;
        const int r6c = (r6 < MG) ? r6 : (MG - 1);
        float b0v = 0.f, b1v = 0.f, b2v = 0.f;
        #pragma unroll 2
        for (int k4 = 0; k4 < 16; ++k4) {
            const float w0 = wreg[k4 * 128 + 0  + f];
            const float w1 = wreg[k4 * 128 + 32 + f];
            const float w2 = wreg[k4 * 128 + 64 + f];
            const float w3 = wreg[k4 * 128 + 96 + f];
            float4 v;
            v = xv[(islot + 128) * 32 + 16 + k4]; b0v += v.x*w0 + v.y*w1 + v.z*w2 + v.w*w3;
            v = xv[(islot + 160) * 32 + 16 + k4]; b1v += v.x*w0 + v.y*w1 + v.z*w2 + v.w*w3;
            v = xv[(r6c        ) * 32 + 16 + k4]; b2v += v.x*w0 + v.y*w1 + v.z*w2 + v.w*w3;
        }
        __syncthreads();
        for (int idx = t; idx < 2048; idx += TPB) wreg[idx] = W1[idx];
        __syncthreads();
        // ---- Group B, K-half 1 ----
        #pragma unroll 2
        for (int k4 = 0; k4 < 16; ++k4) {
            const float w0 = wreg[k4 * 128 + 0  + f];
            const float w1 = wreg[k4 * 128 + 32 + f];
            const float w2 = wreg[k4 * 128 + 64 + f];
            const float w3 = wreg[k4 * 128 + 96 + f];
            float4 v;
            v = xv[(islot + 128) * 32 + k4]; b0v += v.x*w0 + v.y*w1 + v.z*w2 + v.w*w3;
            v = xv[(islot + 160) * 32 + k4]; b1v += v.x*w0 + v.y*w1 + v.z*w2 + v.w*w3;
            v = xv[(r6c        ) * 32 + k4]; b2v += v.x*w0 + v.y*w1 + v.z*w2 + v.w*w3;
        }
        bufX[(islot + 128) * 36 + f] = dinv[islot + 128] * b0v;
        bufX[(islot + 160) * 36 + f] = dinv[islot + 160] * b1v;
        if (r6 < MG) bufX[r6 * 36 + f] = dinv[r6] * b2v;
    }
    __syncthreads();
    agg_layer(0);    // h1 -> arch[:,0:32)
    __syncthreads();

    // ---------------- Layer 2 ----------------
    for (int idx = t; idx < 1024; idx += TPB) wreg[idx] = W2[idx];
    if (t < 32) bias[t] = b2[t];
    __syncthreads();
    gemm_mid(hcur);
    __syncthreads();
    agg_layer(32);   // h2 -> arch[:,32:64)
    __syncthreads();

    // ---------------- Layer 3 ----------------
    for (int idx = t; idx < 1024; idx += TPB) wreg[idx] = W3[idx];
    if (t < 32) bias[t] = b3[t];
    __syncthreads();
    gemm_mid(hcur);
    __syncthreads();
    agg_layer(-1);   // h3 stays in hcur (f32), not archived
    __syncthreads();

    // ---------------- Layer 4 (Fout=1): scl = dinv * (h3 @ W4); scl[200]=0 ----------------
    float* scl = (float*)(smem + OFF_CNT);   // 400 floats available (cnt+cur dead)
    if (t < MG) {
        float a = 0.f;
        #pragma unroll 8
        for (int k = 0; k < 32; ++k) a += hcur[t * 36 + k] * W4[k];
        scl[t] = dinv[t] * a;
    }
    if (t == 512) scl[200] = 0.f;
    __syncthreads();
    if (t < MG) {
        const int p0 = roff[t], p1 = roff[t + 1];
        float s = 0.f;
        for (int p = p0; p < p1; p += 4) {
            const unsigned q = *(const unsigned*)(csr + p);
            s += scl[q & 255u] + scl[(q >> 8) & 255u]
               + scl[(q >> 16) & 255u] + scl[q >> 24];
        }
        h4k[t] = tanhf(dinv[t] * s + b4[0]);
    }
    __syncthreads();

    // ---------------- SortPool: exact stable rank (desc value, asc index) ----------------
    if (t < 512) {
        const int i = t & 255;
        const int half = t >> 8;
        if (i < MG) {
            const float vi = h4k[i];
            int r = 0;
            const int j0 = half * 100, j1 = half * 100 + 100;
            for (int j = j0; j < j1; ++j) {
                const float vj = h4k[j];
                r += (vj > vi || (vj == vi && j < i)) ? 1 : 0;
            }
            atomicAdd(&rank[i], r);
        }
    }
    __syncthreads();
    if (t < MG) {
        const int r = rank[t];
        if (r < 30) ord[r] = t;
    }
    __syncthreads();

    // ---------------- Stage conv weights (bufX tail) + gather top-30 features ----------
    float* topv = bufX;           // [30][100] = 3000 floats
    float* cw   = bufX + 3104;    // cW1: [0,1552)  cW2: [1552,4112); ends at 7216 <= 7236
    for (int idx = t; idx < 1552; idx += TPB) cw[idx] = cW1[idx];
    for (int idx = t; idx < 2560; idx += TPB) cw[1552 + idx] = cW2[idx];
    if (t < 16) bias[t] = cb1[t];
    else if (t < 48) bias[t] = cb2[t - 16];
    for (int idx = t; idx < 2910; idx += TPB) {   // 30*97 grid-stride
        const int kk = idx / 97;
        const int ff = idx - kk * 97;
        const int nd = ord[kk];
        float v;
        if      (ff < 64) v = __half2float(arch[(size_t)(gbase + nd) * 64 + ff]);
        else if (ff < 96) v = hcur[nd * 36 + (ff - 64)];   // h3, f32
        else              v = h4k[nd];
        topv[kk * 100 + ff] = v;
    }
    __syncthreads();

    // conv scratch in hcur (dead after gather barrier)
    float* c1p2 = hcur;           // [16][30]
    float* c1pl = hcur + 480;     // [16][16]
    float* flat = hcur + 736;     // [352]
    float* hlin = hcur + 1088;    // [128]

    // ---------------- Conv1 (97->16 per slot) + ReLU ----------------
    if (t < 480) {
        const int o  = t & 15;
        const int tt = t >> 4;
        float a = bias[o];
        const float* wrow = cw + o * 97;
        const float* trow = topv + tt * 100;
        #pragma unroll 4
        for (int f = 0; f < 97; ++f) a += wrow[f] * trow[f];
        c1p2[o * 30 + tt] = fmaxf(a, 0.f);
    }
    __syncthreads();

    // ---------------- MaxPool1d(2,2): 30 -> 15 ----------------
    if (t < 240) {
        const int o  = t & 15;
        const int tp = t >> 4;
        c1pl[o * 16 + tp] = fmaxf(c1p2[o * 30 + 2 * tp], c1p2[o * 30 + 2 * tp + 1]);
    }
    __syncthreads();

    // ---------------- Conv2 (16->32, k=5) + ReLU -> flat; init hlin ----------------
    if (t < 352) {
        const int o  = t & 31;
        const int tt = t >> 5;
        float a = bias[16 + o];
        const float* w2r = cw + 1552 + o * 80;
        #pragma unroll
        for (int i2 = 0; i2 < 16; ++i2) {
            #pragma unroll
            for (int kk = 0; kk < 5; ++kk)
                a += w2r[i2 * 5 + kk] * c1pl[i2 * 16 + tt + kk];
        }
        flat[o * 11 + tt] = fmaxf(a, 0.f);
    } else if (t >= 512 && t < 640) {
        hlin[t - 512] = lb1[t - 512];
    }
    __syncthreads();

    // ---------------- Linear 352->128 (split-K over 8 groups) ----------------
    {
        const int f  = t & 127;
        const int kc = t >> 7;
        float a = 0.f;
        const int k0 = kc * 44;
        #pragma unroll 4
        for (int kk = k0; kk < k0 + 44; ++kk) a += flat[kk] * lW1[kk * 128 + f];
        atomicAdd(&hlin[f], a);
    }
    __syncthreads();

    // ---------------- ReLU -> Linear 128->1 -> sigmoid ----------------
    if (t < 128) {
        float p = fmaxf(hlin[t], 0.f) * lW2[t];
        #pragma unroll
        for (int off = 32; off > 0; off >>= 1) p += __shfl_down(p, off);
        if ((t & 63) == 0) red[t >> 6] = p;
    }
    __syncthreads();
    if (t == 0) {
        const float z = red[0] + red[1] + lb2[0];
        out[g] = 1.f / (1.f + expf(-z));
    }
}

extern "C" void kernel_launch(void* const* d_in, const int* in_sizes, int n_in,
                              void* d_out, int out_size, void* d_ws, size_t ws_size,
                              hipStream_t stream) {
    (void)in_sizes; (void)n_in; (void)out_size; (void)ws_size;
    const float* x   = (const float*)d_in[0];
    const int*   ei  = (const int*)d_in[1];
    const float* W1  = (const float*)d_in[3];  const float* b1  = (const float*)d_in[4];
    const float* W2  = (const float*)d_in[5];  const float* b2  = (const float*)d_in[6];
    const float* W3  = (const float*)d_in[7];  const float* b3  = (const float*)d_in[8];
    const float* W4  = (const float*)d_in[9];  const float* b4  = (const float*)d_in[10];
    const float* cW1 = (const float*)d_in[11]; const float* cb1 = (const float*)d_in[12];
    const float* cW2 = (const float*)d_in[13]; const float* cb2 = (const float*)d_in[14];
    const float* lW1 = (const float*)d_in[15]; const float* lb1 = (const float*)d_in[16];
    const float* lW2 = (const float*)d_in[17]; const float* lb2 = (const float*)d_in[18];
    float* out = (float*)d_out;
    __half* arch = (__half*)d_ws;   // needs 512*200*64*2 = 13.1 MB

    hipFuncSetAttribute((const void*)dgcnn_kernel,
                        hipFuncAttributeMaxDynamicSharedMemorySize, SMEM_BYTES);

    dgcnn_kernel<<<GRID, TPB, SMEM_BYTES, stream>>>(
        x, ei, W1, b1, W2, b2, W3, b3, W4, b4,
        cW1, cb1, cW2, cb2, lW1, lb1, lW2, lb2, arch, out);
}